// Round 5
// baseline (1246.562 us; speedup 1.0000x reference)
//
#include <hip/hip_runtime.h>
#include <math.h>

#define NB 8
#define NA 720
#define ND 1024
#define NH 512
#define NW 512

#define DTH_D (3.14159265358979323846 / 720.0)

using h2v = decltype(__builtin_amdgcn_cvt_pkrtz(0.0f, 0.0f));
static_assert(sizeof(h2v) == 4, "h2v must be 4 bytes");

// ---------------- Kernel 1: 11-tap conv along detector, left pad 10, *DTH ---------------
__global__ __launch_bounds__(256) void conv_kernel(const float* __restrict__ x,
                                                   const float* __restrict__ w,
                                                   float* __restrict__ y) {
    int row = blockIdx.x;                 // b*720 + a
    const float* xr = x + (size_t)row * ND;
    float* yr = y + (size_t)row * ND;

    __shared__ float s[16 + ND];
    __shared__ float wk[16];

    int tid = threadIdx.x;
    if (tid < 16) s[tid] = 0.0f;
    if (tid < 11) wk[tid] = w[tid] * (float)DTH_D;

    float4 v = ((const float4*)xr)[tid];
    *(float4*)&s[16 + tid * 4] = v;
    __syncthreads();

    int d0 = tid * 4;
    float o0 = 0.f, o1 = 0.f, o2 = 0.f, o3 = 0.f;
#pragma unroll
    for (int k = 0; k < 11; ++k) {
        float wv = wk[k];
        o0 = fmaf(wv, s[6 + d0 + k], o0);
        o1 = fmaf(wv, s[7 + d0 + k], o1);
        o2 = fmaf(wv, s[8 + d0 + k], o2);
        o3 = fmaf(wv, s[9 + d0 + k], o3);
    }
    *(float4*)&yr[d0] = make_float4(o0, o1, o2, o3);
}

// ---------------- Kernel 2: per-angle tables: cos, sin, C = 511.5 - 255.5*(cos+sin) ----
// u (fractional detector index) = i*cos + j*sin + C  for pixel (i,j).
__global__ void table_kernel(float* __restrict__ ct, float* __restrict__ st,
                             float* __restrict__ cc) {
    int a = blockIdx.x * blockDim.x + threadIdx.x;
    if (a < NA) {
        float th = (float)((a + 0.5) * DTH_D);
        double thd = (double)th;
        double c = cos(thd), s = sin(thd);
        ct[a] = (float)c;
        st[a] = (float)s;
        cc[a] = (float)(511.5 - 255.5 * (c + s));
    }
}

// ---------------- Kernel 3: backprojection ---------------
// 256 blocks = 8 batches x (4 i-tiles x 8 j-tiles). Tile = 128 i x 64 j.
// 512 threads: lane = j (stride-1 -> conflict-free LDS, R1-verified), wave wv
// covers i = ibase + wv*16 + r (r=0..15).
// LDS rows packed as f16 dword entries e_d = (v_d, v_{d+1}-v_d): ONE ds_read_b32
// per pixel-angle; interp = one v_dot2_f32_f16 with (1.0, g).

__device__ __forceinline__ void async_ld16(const float* g, float* l) {
    __builtin_amdgcn_global_load_lds((const __attribute__((address_space(1))) void*)g,
                                     (__attribute__((address_space(3))) void*)l,
                                     16, 0, 0);
}

// vmcnt(0) only (lgkm/exp untouched), then barrier
#define WAIT_VM0_BARRIER() do { \
    asm volatile("" ::: "memory"); \
    __builtin_amdgcn_s_waitcnt(0x0F70); \
    __builtin_amdgcn_s_barrier(); \
    asm volatile("" ::: "memory"); \
} while (0)

// lgkmcnt(0) only (vm loads stay in flight), then barrier
#define WAIT_LGKM_BARRIER() do { \
    asm volatile("" ::: "memory"); \
    __builtin_amdgcn_s_waitcnt(0xC70F); \
    __builtin_amdgcn_s_barrier(); \
    asm volatile("" ::: "memory"); \
} while (0)

static __device__ __forceinline__ float fractf_(float x) {
#if __has_builtin(__builtin_amdgcn_fractf)
    return __builtin_amdgcn_fractf(x);
#else
    return x - floorf(x);
#endif
}

static __device__ __forceinline__ unsigned pk_f16(float v, float d) {
    h2v h = __builtin_amdgcn_cvt_pkrtz(v, d);
    return __builtin_bit_cast(unsigned, h);
}

#define NCH 90   // chunks of 8 angle rows

__global__ __launch_bounds__(512) void bp_kernel(const float* __restrict__ sino,
                                                 const float* __restrict__ ct,
                                                 const float* __restrict__ st,
                                                 const float* __restrict__ cc,
                                                 float* __restrict__ out) {
    int bid = blockIdx.x;
    int b = bid >> 5;                  // 0..7
    int tile = bid & 31;
    int ibase = (tile >> 3) * 128;     // 4 i-tiles
    int jbase = (tile & 7) * 64;       // 8 j-tiles

    int tid = threadIdx.x;
    int lane = tid & 63;
    int wv = tid >> 6;                 // 0..7

    int j = jbase + lane;
    float fj = (float)j;
    float fi0 = (float)(ibase + wv * 16);

    __shared__ unsigned cop[2][8][1024];   // 64 KB packed rows (dbuf)
    __shared__ float raw[8][1028];         // 32.9 KB staging (single buffer + pad)

    const float* srow = sino + (size_t)b * (NA * ND);

    // zero the neighbor pads (raw[r][1024] used as v_1024 = 0)
    if (tid < 32) raw[tid >> 2][1024 + (tid & 3)] = 0.0f;

    float acc[16];
#pragma unroll
    for (int r = 0; r < 16; ++r) acc[r] = 0.0f;

    int d0 = lane * 16;   // dword span this lane repacks within its wave's row

    // ---- prologue ----
    // load chunk 0 (wave wv stages angle row wv)
    {
        const float* rp = srow + (size_t)wv * ND + lane * 4;
        float* lp = &raw[wv][lane * 4];
#pragma unroll
        for (int p = 0; p < 4; ++p) async_ld16(rp + p * 256, lp + p * 256);
    }
    __syncthreads();   // full drain: pad writes + chunk0 loads

    // repack chunk 0 -> cop[0]
    {
        const float* rw = &raw[wv][0];
        float4 a0 = *(const float4*)&rw[d0];
        float4 a1 = *(const float4*)&rw[d0 + 4];
        float4 a2 = *(const float4*)&rw[d0 + 8];
        float4 a3 = *(const float4*)&rw[d0 + 12];
        float nb = rw[d0 + 16];
        uint4* cw = (uint4*)&cop[0][wv][d0];
        cw[0] = make_uint4(pk_f16(a0.x, a0.y - a0.x), pk_f16(a0.y, a0.z - a0.y),
                           pk_f16(a0.z, a0.w - a0.z), pk_f16(a0.w, a1.x - a0.w));
        cw[1] = make_uint4(pk_f16(a1.x, a1.y - a1.x), pk_f16(a1.y, a1.z - a1.y),
                           pk_f16(a1.z, a1.w - a1.z), pk_f16(a1.w, a2.x - a1.w));
        cw[2] = make_uint4(pk_f16(a2.x, a2.y - a2.x), pk_f16(a2.y, a2.z - a2.y),
                           pk_f16(a2.z, a2.w - a2.z), pk_f16(a2.w, a3.x - a2.w));
        cw[3] = make_uint4(pk_f16(a3.x, a3.y - a3.x), pk_f16(a3.y, a3.z - a3.y),
                           pk_f16(a3.z, a3.w - a3.z), pk_f16(a3.w, nb - a3.w));
    }
    WAIT_LGKM_BARRIER();     // repack done; raw free for reuse

    // start loads for chunk 1
    {
        const float* rp = srow + (size_t)(8 + wv) * ND + lane * 4;
        float* lp = &raw[wv][lane * 4];
#pragma unroll
        for (int p = 0; p < 4; ++p) async_ld16(rp + p * 256, lp + p * 256);
    }

    for (int c = 0; c < NCH; ++c) {
        int cur = c & 1;
        unsigned cbase = cur ? 32768u : 0u;   // byte offset of cop[cur]
        const char* cb0 = (const char*)&cop[0][0][0];
        // ---- compute: 8 angles from cop[cur] ----
#pragma unroll
        for (int k = 0; k < 8; ++k) {
            int ang = c * 8 + k;
            float ca = ct[ang];
            float sa = st[ang];
            float Cc = cc[ang];
            const char* cb = cb0 + cbase + (unsigned)(k * 4096);
            float u0 = fmaf(fi0, ca, fmaf(fj, sa, Cc));
#pragma unroll
            for (int r = 0; r < 16; ++r) {
                float ur = fmaf((float)r, ca, u0);
                int iu = (int)ur;                  // u in [149,874): trunc == floor
                float g = fractf_(ur);
                unsigned w = *(const unsigned*)(cb + ((unsigned)iu << 2));
                h2v hw = __builtin_bit_cast(h2v, w);
#if __has_builtin(__builtin_amdgcn_fdot2)
                h2v gg = __builtin_amdgcn_cvt_pkrtz(1.0f, g);
                acc[r] = __builtin_amdgcn_fdot2(hw, gg, acc[r], false);
#else
                acc[r] = fmaf(g, (float)hw.y, acc[r]);
                acc[r] += (float)hw.x;
#endif
            }
        }
        if (c == NCH - 1) break;

        WAIT_VM0_BARRIER();      // loads(c+1) landed in raw

        // ---- repack chunk c+1 -> cop[cur^1] ----
        {
            const float* rw = &raw[wv][0];
            float4 a0 = *(const float4*)&rw[d0];
            float4 a1 = *(const float4*)&rw[d0 + 4];
            float4 a2 = *(const float4*)&rw[d0 + 8];
            float4 a3 = *(const float4*)&rw[d0 + 12];
            float nb = rw[d0 + 16];
            uint4* cw = (uint4*)&cop[cur ^ 1][wv][d0];
            cw[0] = make_uint4(pk_f16(a0.x, a0.y - a0.x), pk_f16(a0.y, a0.z - a0.y),
                               pk_f16(a0.z, a0.w - a0.z), pk_f16(a0.w, a1.x - a0.w));
            cw[1] = make_uint4(pk_f16(a1.x, a1.y - a1.x), pk_f16(a1.y, a1.z - a1.y),
                               pk_f16(a1.z, a1.w - a1.z), pk_f16(a1.w, a2.x - a1.w));
            cw[2] = make_uint4(pk_f16(a2.x, a2.y - a2.x), pk_f16(a2.y, a2.z - a2.y),
                               pk_f16(a2.z, a2.w - a2.z), pk_f16(a2.w, a3.x - a2.w));
            cw[3] = make_uint4(pk_f16(a3.x, a3.y - a3.x), pk_f16(a3.y, a3.z - a3.y),
                               pk_f16(a3.z, a3.w - a3.z), pk_f16(a3.w, nb - a3.w));
        }
        WAIT_LGKM_BARRIER();     // repack reads/writes drained; raw reusable

        // ---- start loads for chunk c+2 ----
        if (c + 2 < NCH) {
            const float* rp = srow + (size_t)((c + 2) * 8 + wv) * ND + lane * 4;
            float* lp = &raw[wv][lane * 4];
#pragma unroll
            for (int p = 0; p < 4; ++p) async_ld16(rp + p * 256, lp + p * 256);
        }
    }

    float* orow = out + (size_t)b * (NH * NW);
#pragma unroll
    for (int r = 0; r < 16; ++r) {
        int i = ibase + wv * 16 + r;
        orow[(size_t)i * NW + j] = acc[r];
    }
}

extern "C" void kernel_launch(void* const* d_in, const int* in_sizes, int n_in,
                              void* d_out, int out_size, void* d_ws, size_t ws_size,
                              hipStream_t stream) {
    const float* x = (const float*)d_in[0];      // [8,1,720,1024] f32
    const float* w = (const float*)d_in[1];      // [1,1,1,11] f32
    float* out = (float*)d_out;                  // [8,1,512,512] f32
    float* ws = (float*)d_ws;

    float* sino = ws;                            // 8*720*1024 floats
    float* ct = ws + (size_t)NB * NA * ND;
    float* st = ct + NA;
    float* cc = st + NA;

    conv_kernel<<<dim3(NB * NA), dim3(256), 0, stream>>>(x, w, sino);
    table_kernel<<<dim3(3), dim3(256), 0, stream>>>(ct, st, cc);
    bp_kernel<<<dim3(256), dim3(512), 0, stream>>>(sino, ct, st, cc, out);
}

// Round 6
// 695.605 us; speedup vs baseline: 1.7921x; 1.7921x over previous
//
#include <hip/hip_runtime.h>
#include <math.h>

#define NB 8
#define NA 720
#define ND 1024
#define NH 512
#define NW 512

#define DTH_D (3.14159265358979323846 / 720.0)

using h2v = decltype(__builtin_amdgcn_cvt_pkrtz(0.0f, 0.0f));
static_assert(sizeof(h2v) == 4, "h2v must be 4 bytes");

// ---------------- Kernel 1: 11-tap conv along detector, left pad 10, *DTH ---------------
__global__ __launch_bounds__(256) void conv_kernel(const float* __restrict__ x,
                                                   const float* __restrict__ w,
                                                   float* __restrict__ y) {
    int row = blockIdx.x;                 // b*720 + a
    const float* xr = x + (size_t)row * ND;
    float* yr = y + (size_t)row * ND;

    __shared__ float s[16 + ND];
    __shared__ float wk[16];

    int tid = threadIdx.x;
    if (tid < 16) s[tid] = 0.0f;
    if (tid < 11) wk[tid] = w[tid] * (float)DTH_D;

    float4 v = ((const float4*)xr)[tid];
    *(float4*)&s[16 + tid * 4] = v;
    __syncthreads();

    int d0 = tid * 4;
    float o0 = 0.f, o1 = 0.f, o2 = 0.f, o3 = 0.f;
#pragma unroll
    for (int k = 0; k < 11; ++k) {
        float wv = wk[k];
        o0 = fmaf(wv, s[6 + d0 + k], o0);
        o1 = fmaf(wv, s[7 + d0 + k], o1);
        o2 = fmaf(wv, s[8 + d0 + k], o2);
        o3 = fmaf(wv, s[9 + d0 + k], o3);
    }
    *(float4*)&yr[d0] = make_float4(o0, o1, o2, o3);
}

// ---------------- Kernel 2: per-angle tables: cos, sin, C = 511.5 - 255.5*(cos+sin) ----
// u (fractional detector index) = i*cos + j*sin + C  for pixel (i,j).
__global__ void table_kernel(float* __restrict__ ct, float* __restrict__ st,
                             float* __restrict__ cc) {
    int a = blockIdx.x * blockDim.x + threadIdx.x;
    if (a < NA) {
        float th = (float)((a + 0.5) * DTH_D);
        double thd = (double)th;
        double c = cos(thd), s = sin(thd);
        ct[a] = (float)c;
        st[a] = (float)s;
        cc[a] = (float)(511.5 - 255.5 * (c + s));
    }
}

// ---------------- Kernel 3: backprojection ---------------
// 256 blocks = 8 batches x (4 i-tiles x 8 j-tiles). Tile = 128 i x 64 j.
// 512 threads: lane = j (adjacent lanes -> same/adjacent LDS dwords: broadcast
// or 2-way = conflict-free, R1-verified), wave wv covers i = ibase+wv*16+r.
// LDS rows packed as f16 dword entries e_d = (v_d, v_{d+1}-v_d): ONE ds_read_b32
// per pixel-angle; interp = one v_dot2_f32_f16 with (1.0, g). Serial u += cos
// chain per r keeps register pressure low (R5 spilled with parallel chains).

__device__ __forceinline__ void async_ld16(const float* g, float* l) {
    __builtin_amdgcn_global_load_lds((const __attribute__((address_space(1))) void*)g,
                                     (__attribute__((address_space(3))) void*)l,
                                     16, 0, 0);
}

// per-wave wait: all my global_load_lds done (vmcnt=0, exp=7, lgkm=15 no-wait)
#define WAIT_VM0() do { \
    asm volatile("" ::: "memory"); \
    __builtin_amdgcn_s_waitcnt(0x0F70); \
    asm volatile("" ::: "memory"); \
} while (0)

// lgkmcnt(0) only (vm loads stay in flight: vm=63, exp=7), then barrier
#define WAIT_LGKM_BARRIER() do { \
    asm volatile("" ::: "memory"); \
    __builtin_amdgcn_s_waitcnt(0xC07F); \
    __builtin_amdgcn_s_barrier(); \
    asm volatile("" ::: "memory"); \
} while (0)

static __device__ __forceinline__ float fractf_(float x) {
#if __has_builtin(__builtin_amdgcn_fractf)
    return __builtin_amdgcn_fractf(x);
#else
    return x - floorf(x);
#endif
}

static __device__ __forceinline__ unsigned pk_f16(float v, float d) {
    h2v h = __builtin_amdgcn_cvt_pkrtz(v, d);
    return __builtin_bit_cast(unsigned, h);
}

#define NCH 90   // chunks of 8 angle rows

__global__ __launch_bounds__(512) void bp_kernel(const float* __restrict__ sino,
                                                 const float* __restrict__ ct,
                                                 const float* __restrict__ st,
                                                 const float* __restrict__ cc,
                                                 float* __restrict__ out) {
    int bid = blockIdx.x;
    int b = bid >> 5;                  // 0..7
    int tile = bid & 31;
    int ibase = (tile >> 3) * 128;     // 4 i-tiles
    int jbase = (tile & 7) * 64;       // 8 j-tiles

    int tid = threadIdx.x;
    int lane = tid & 63;
    int wv = tid >> 6;                 // 0..7

    int j = jbase + lane;
    float fj = (float)j;
    float fi0 = (float)(ibase + wv * 16);

    __shared__ unsigned cop[2][8][1024];   // 64 KB packed rows (dbuf)
    __shared__ float raw[8][1028];         // 32.9 KB staging (wave-private rows + pad)

    const float* srow = sino + (size_t)b * (NA * ND);

    // zero the neighbor pads (raw[r][1024] used as v_1024 source; value unused
    // downstream since u < 874, but must not be NaN/poison for pk_f16)
    if (tid < 32) raw[tid >> 2][1024 + (tid & 3)] = 0.0f;

    float acc[16];
#pragma unroll
    for (int r = 0; r < 16; ++r) acc[r] = 0.0f;

    // ---- prologue ----
    {
        const float* rp = srow + (size_t)wv * ND + lane * 4;
        float* lp = &raw[wv][lane * 4];
#pragma unroll
        for (int p = 0; p < 4; ++p) async_ld16(rp + p * 256, lp + p * 256);
    }
    __syncthreads();   // full drain: pad writes + chunk0 loads

    // repack chunk 0 -> cop[0]  (lane*4 stride: canonical conflict-free b128)
#pragma unroll 1
    for (int p = 0; p < 4; ++p) {
        int d = p * 256 + lane * 4;
        const float* rw = &raw[wv][0];
        float4 a0 = *(const float4*)&rw[d];
        float nb = rw[d + 4];
        *(uint4*)&cop[0][wv][d] =
            make_uint4(pk_f16(a0.x, a0.y - a0.x), pk_f16(a0.y, a0.z - a0.y),
                       pk_f16(a0.z, a0.w - a0.z), pk_f16(a0.w, nb - a0.w));
    }
    WAIT_LGKM_BARRIER();     // repack visible to all; raw free for reuse

    // start loads for chunk 1
    {
        const float* rp = srow + (size_t)(8 + wv) * ND + lane * 4;
        float* lp = &raw[wv][lane * 4];
#pragma unroll
        for (int p = 0; p < 4; ++p) async_ld16(rp + p * 256, lp + p * 256);
    }

    for (int c = 0; c < NCH; ++c) {
        int cur = c & 1;
        const char* cb0 = (const char*)&cop[0][0][0] + (cur ? 32768u : 0u);
        // ---- compute: 8 angles from cop[cur] ----
#pragma unroll
        for (int k = 0; k < 8; ++k) {
            int ang = c * 8 + k;
            float ca = ct[ang];
            float sa = st[ang];
            float Cc = cc[ang];
            const char* cb = cb0 + (unsigned)(k * 4096);
            float u = fmaf(fi0, ca, fmaf(fj, sa, Cc));
#pragma unroll
            for (int r = 0; r < 16; ++r) {
                int iu = (int)u;                  // u in [149,874): trunc == floor
                float g = fractf_(u);
                unsigned w = *(const unsigned*)(cb + ((unsigned)iu << 2));
                h2v hw = __builtin_bit_cast(h2v, w);
#if __has_builtin(__builtin_amdgcn_fdot2)
                h2v gg = __builtin_amdgcn_cvt_pkrtz(1.0f, g);
                acc[r] = __builtin_amdgcn_fdot2(hw, gg, acc[r], false);
#else
                acc[r] = fmaf(g, (float)hw.y, acc[r]);
                acc[r] += (float)hw.x;
#endif
                u += ca;
            }
        }
        if (c == NCH - 1) break;

        WAIT_VM0();              // my loads(c+1) landed in my raw row (wave-private)

        // ---- repack chunk c+1 -> cop[cur^1] ----
#pragma unroll 1
        for (int p = 0; p < 4; ++p) {
            int d = p * 256 + lane * 4;
            const float* rw = &raw[wv][0];
            float4 a0 = *(const float4*)&rw[d];
            float nb = rw[d + 4];
            *(uint4*)&cop[cur ^ 1][wv][d] =
                make_uint4(pk_f16(a0.x, a0.y - a0.x), pk_f16(a0.y, a0.z - a0.y),
                           pk_f16(a0.z, a0.w - a0.z), pk_f16(a0.w, nb - a0.w));
        }
        WAIT_LGKM_BARRIER();     // repack drained + all waves synced; raw reusable

        // ---- start loads for chunk c+2 ----
        if (c + 2 < NCH) {
            const float* rp = srow + (size_t)((c + 2) * 8 + wv) * ND + lane * 4;
            float* lp = &raw[wv][lane * 4];
#pragma unroll
            for (int p = 0; p < 4; ++p) async_ld16(rp + p * 256, lp + p * 256);
        }
    }

    float* orow = out + (size_t)b * (NH * NW);
#pragma unroll
    for (int r = 0; r < 16; ++r) {
        int i = ibase + wv * 16 + r;
        orow[(size_t)i * NW + j] = acc[r];
    }
}

extern "C" void kernel_launch(void* const* d_in, const int* in_sizes, int n_in,
                              void* d_out, int out_size, void* d_ws, size_t ws_size,
                              hipStream_t stream) {
    const float* x = (const float*)d_in[0];      // [8,1,720,1024] f32
    const float* w = (const float*)d_in[1];      // [1,1,1,11] f32
    float* out = (float*)d_out;                  // [8,1,512,512] f32
    float* ws = (float*)d_ws;

    float* sino = ws;                            // 8*720*1024 floats
    float* ct = ws + (size_t)NB * NA * ND;
    float* st = ct + NA;
    float* cc = st + NA;

    conv_kernel<<<dim3(NB * NA), dim3(256), 0, stream>>>(x, w, sino);
    table_kernel<<<dim3(3), dim3(256), 0, stream>>>(ct, st, cc);
    bp_kernel<<<dim3(256), dim3(512), 0, stream>>>(sino, ct, st, cc, out);
}